// Round 7
// baseline (300.346 us; speedup 1.0000x reference)
//
#include <hip/hip_runtime.h>

#define N_NODES 50000
#define SCAN_BLK 256
#define NBLK ((N_NODES + SCAN_BLK - 1) / SCAN_BLK)   // 196

// ---- CSR build ----
__global__ void cnt_kernel(const int* __restrict__ dst, int E, int* __restrict__ cnt) {
    int e = blockIdx.x * blockDim.x + threadIdx.x;
    if (e < E) atomicAdd(&cnt[dst[e]], 1);
}

__global__ void bsum_kernel(const int* __restrict__ cnt, int* __restrict__ bsum, int n) {
    __shared__ int sh[SCAN_BLK];
    int i = blockIdx.x * SCAN_BLK + threadIdx.x;
    sh[threadIdx.x] = (i < n) ? cnt[i] : 0;
    __syncthreads();
    for (int off = SCAN_BLK / 2; off > 0; off >>= 1) {
        if (threadIdx.x < off) sh[threadIdx.x] += sh[threadIdx.x + off];
        __syncthreads();
    }
    if (threadIdx.x == 0) bsum[blockIdx.x] = sh[0];
}

__global__ void bscan_kernel(const int* __restrict__ bsum, int* __restrict__ bbase, int nblk) {
    __shared__ int sh[SCAN_BLK];
    int tid = threadIdx.x;
    int v = (tid < nblk) ? bsum[tid] : 0;
    sh[tid] = v;
    __syncthreads();
    for (int off = 1; off < SCAN_BLK; off <<= 1) {
        int t = (tid >= off) ? sh[tid - off] : 0;
        __syncthreads();
        sh[tid] += t;
        __syncthreads();
    }
    if (tid < nblk) bbase[tid] = sh[tid] - v;   // exclusive
}

// per-block exclusive scan + rowptr/cursor emit + dis = rsqrt(cnt+1)
__global__ void scatter_scan_kernel(const int* __restrict__ cnt, const int* __restrict__ bbase,
                                    int* __restrict__ rowptr, int* __restrict__ cursor,
                                    float* __restrict__ dis, int n) {
    __shared__ int sh[SCAN_BLK];
    int tid = threadIdx.x;
    int i = blockIdx.x * SCAN_BLK + tid;
    int v = (i < n) ? cnt[i] : 0;
    sh[tid] = v;
    __syncthreads();
    for (int off = 1; off < SCAN_BLK; off <<= 1) {
        int t = (tid >= off) ? sh[tid - off] : 0;
        __syncthreads();
        sh[tid] += t;
        __syncthreads();
    }
    int excl = bbase[blockIdx.x] + sh[tid] - v;
    if (i < n) {
        rowptr[i] = excl;
        cursor[i] = excl;
        dis[i] = rsqrtf((float)v + 1.0f);
        if (i == n - 1) rowptr[n] = excl + v;
    }
}

__global__ void fill_kernel(const int* __restrict__ src, const int* __restrict__ dst,
                            int E, int* __restrict__ cursor, int* __restrict__ col) {
    int e = blockIdx.x * blockDim.x + threadIdx.x;
    if (e < E) {
        int pos = atomicAdd(&cursor[dst[e]], 1);
        col[pos] = src[e];
    }
}

// ---- register-blocked fp32 MM: Y = X[n,K] @ W[K,64], opt *dis[row], +bias, relu ----
// 256 threads; block tile 32 rows x 64 cols; thread tile 2 rows x 4 cols.
// 1563 blocks -> ~24 waves/CU.
template<int K, bool RELU, bool BIAS, bool SCALE>
__global__ __launch_bounds__(256) void mm_tiled(const float* __restrict__ X,
        const float* __restrict__ W, const float* __restrict__ bias,
        const float* __restrict__ dis, float* __restrict__ Y, int n) {
    constexpr int KC = 64;
    __shared__ float xs[32][KC + 1];
    const int tid = threadIdx.x;
    const int j4 = tid & 15;          // col group -> cols j4*4..+3
    const int rp = tid >> 4;          // row pair -> rows rp*2, rp*2+1
    const int row0 = blockIdx.x * 32;
    const int col0 = j4 * 4;
    float acc[2][4] = {};

    for (int kc = 0; kc < K; kc += KC) {
        __syncthreads();
        #pragma unroll
        for (int it = 0; it < 2; ++it) {
            int idx = it * 256 + tid;           // 512 float4 slots = 32 rows x 16
            int r = idx >> 4, c4 = idx & 15;
            int row = row0 + r;
            float4 v = make_float4(0.f, 0.f, 0.f, 0.f);
            if (row < n) v = *reinterpret_cast<const float4*>(&X[(size_t)row * K + kc + c4 * 4]);
            xs[r][c4 * 4 + 0] = v.x; xs[r][c4 * 4 + 1] = v.y;
            xs[r][c4 * 4 + 2] = v.z; xs[r][c4 * 4 + 3] = v.w;
        }
        __syncthreads();
        #pragma unroll 16
        for (int k = 0; k < KC; ++k) {
            const float4 w = *reinterpret_cast<const float4*>(&W[(size_t)(kc + k) * 64 + col0]);
            const float x0 = xs[rp * 2 + 0][k];
            const float x1 = xs[rp * 2 + 1][k];
            acc[0][0] = fmaf(x0, w.x, acc[0][0]);
            acc[0][1] = fmaf(x0, w.y, acc[0][1]);
            acc[0][2] = fmaf(x0, w.z, acc[0][2]);
            acc[0][3] = fmaf(x0, w.w, acc[0][3]);
            acc[1][0] = fmaf(x1, w.x, acc[1][0]);
            acc[1][1] = fmaf(x1, w.y, acc[1][1]);
            acc[1][2] = fmaf(x1, w.z, acc[1][2]);
            acc[1][3] = fmaf(x1, w.w, acc[1][3]);
        }
    }

    float bv[4];
    if (BIAS) {
        #pragma unroll
        for (int c = 0; c < 4; ++c) bv[c] = bias[col0 + c];
    }
    #pragma unroll
    for (int r = 0; r < 2; ++r) {
        int row = row0 + rp * 2 + r;
        if (row < n) {
            float s = SCALE ? dis[row] : 1.0f;
            float o[4];
            #pragma unroll
            for (int c = 0; c < 4; ++c) {
                float v = SCALE ? acc[r][c] * s : acc[r][c];
                if (BIAS) v += bv[c];
                if (RELU) v = fmaxf(v, 0.0f);
                o[c] = v;
            }
            *reinterpret_cast<float4*>(&Y[(size_t)row * 64 + col0]) =
                make_float4(o[0], o[1], o[2], o[3]);
        }
    }
}

// ---- fused FFN head: out = relu(X@Wf1 + bf1) @ Wf2 + bf2  (K=64, mid=64, out=10) ----
// 32 rows per block, same 2x4 tiling for stage 1.
__global__ __launch_bounds__(256) void ffn_kernel(const float* __restrict__ X,
        const float* __restrict__ Wf1, const float* __restrict__ bf1,
        const float* __restrict__ Wf2, const float* __restrict__ bf2,
        float* __restrict__ out, int n) {
    constexpr int KC = 64;
    __shared__ float xs[32][KC + 1];
    __shared__ float h1[32][65];
    const int tid = threadIdx.x;
    const int j4 = tid & 15;
    const int rp = tid >> 4;
    const int row0 = blockIdx.x * 32;
    const int col0 = j4 * 4;
    float acc[2][4] = {};

    #pragma unroll
    for (int it = 0; it < 2; ++it) {
        int idx = it * 256 + tid;
        int r = idx >> 4, c4 = idx & 15;
        int row = row0 + r;
        float4 v = make_float4(0.f, 0.f, 0.f, 0.f);
        if (row < n) v = *reinterpret_cast<const float4*>(&X[(size_t)row * 64 + c4 * 4]);
        xs[r][c4 * 4 + 0] = v.x; xs[r][c4 * 4 + 1] = v.y;
        xs[r][c4 * 4 + 2] = v.z; xs[r][c4 * 4 + 3] = v.w;
    }
    __syncthreads();
    #pragma unroll 16
    for (int k = 0; k < KC; ++k) {
        const float4 w = *reinterpret_cast<const float4*>(&Wf1[(size_t)k * 64 + col0]);
        const float x0 = xs[rp * 2 + 0][k];
        const float x1 = xs[rp * 2 + 1][k];
        acc[0][0] = fmaf(x0, w.x, acc[0][0]);
        acc[0][1] = fmaf(x0, w.y, acc[0][1]);
        acc[0][2] = fmaf(x0, w.z, acc[0][2]);
        acc[0][3] = fmaf(x0, w.w, acc[0][3]);
        acc[1][0] = fmaf(x1, w.x, acc[1][0]);
        acc[1][1] = fmaf(x1, w.y, acc[1][1]);
        acc[1][2] = fmaf(x1, w.z, acc[1][2]);
        acc[1][3] = fmaf(x1, w.w, acc[1][3]);
    }
    #pragma unroll
    for (int c = 0; c < 4; ++c) {
        float b = bf1[col0 + c];
        h1[rp * 2 + 0][col0 + c] = fmaxf(acc[0][c] + b, 0.0f);
        h1[rp * 2 + 1][col0 + c] = fmaxf(acc[1][c] + b, 0.0f);
    }
    __syncthreads();

    // stage 2: out[row, 0..9] = h1[row,:] @ Wf2 + bf2 ; 8 threads/row, 5 of 8 active
    const int lr = tid >> 3;          // 0..31
    const int cg = tid & 7;           // col pair cg -> cols cg*2, cg*2+1
    if (cg < 5) {
        float a0 = bf2[cg * 2 + 0], a1 = bf2[cg * 2 + 1];
        #pragma unroll 16
        for (int k = 0; k < 64; ++k) {
            float xv = h1[lr][k];
            a0 = fmaf(xv, Wf2[(size_t)k * 10 + cg * 2 + 0], a0);
            a1 = fmaf(xv, Wf2[(size_t)k * 10 + cg * 2 + 1], a1);
        }
        int row = row0 + lr;
        if (row < n) {
            out[(size_t)row * 10 + cg * 2 + 0] = a0;
            out[(size_t)row * 10 + cg * 2 + 1] = a1;
        }
    }
}

// ---- CSR aggregate + finalize: out[d,j] = relu(dis[d]*(sum_in hp[s,j] + hp[d,j]) + b[j])
__global__ void csr_agg_kernel(const float* __restrict__ hp, const int* __restrict__ rowptr,
                               const int* __restrict__ col, const float* __restrict__ dis,
                               const float* __restrict__ b, float* __restrict__ out, int n) {
    const int tid = threadIdx.x;
    const int w = tid >> 6, j = tid & 63;
    const int d = blockIdx.x * 4 + w;
    if (d >= n) return;
    const int beg = rowptr[d], end = rowptr[d + 1];
    const int deg = end - beg;
    float acc = hp[(size_t)d * 64 + j];   // self-loop term
    int base = 0;
    while (base < deg) {
        int idx = base + j;
        int c = (idx < deg) ? col[beg + idx] : 0;
        int m = min(64, deg - base);
        int e = 0;
        for (; e + 8 <= m; e += 8) {
            int s0 = __shfl(c, e + 0), s1 = __shfl(c, e + 1);
            int s2 = __shfl(c, e + 2), s3 = __shfl(c, e + 3);
            int s4 = __shfl(c, e + 4), s5 = __shfl(c, e + 5);
            int s6 = __shfl(c, e + 6), s7 = __shfl(c, e + 7);
            float v0 = hp[(size_t)s0 * 64 + j], v1 = hp[(size_t)s1 * 64 + j];
            float v2 = hp[(size_t)s2 * 64 + j], v3 = hp[(size_t)s3 * 64 + j];
            float v4 = hp[(size_t)s4 * 64 + j], v5 = hp[(size_t)s5 * 64 + j];
            float v6 = hp[(size_t)s6 * 64 + j], v7 = hp[(size_t)s7 * 64 + j];
            acc += ((v0 + v1) + (v2 + v3)) + ((v4 + v5) + (v6 + v7));
        }
        for (; e < m; ++e) {
            int s = __shfl(c, e);
            acc += hp[(size_t)s * 64 + j];
        }
        base += 64;
    }
    out[(size_t)d * 64 + j] = fmaxf(dis[d] * acc + b[j], 0.0f);
}

extern "C" void kernel_launch(void* const* d_in, const int* in_sizes, int n_in,
                              void* d_out, int out_size, void* d_ws, size_t ws_size,
                              hipStream_t stream) {
    const float* x   = (const float*)d_in[0];
    const int*   ei  = (const int*)d_in[1];
    const float* W1  = (const float*)d_in[2];
    const float* b1  = (const float*)d_in[3];
    const float* W2  = (const float*)d_in[4];
    const float* b2  = (const float*)d_in[5];
    const float* W3  = (const float*)d_in[6];
    const float* b3  = (const float*)d_in[7];
    const float* Wf1 = (const float*)d_in[8];
    const float* bf1 = (const float*)d_in[9];
    const float* Wf2 = (const float*)d_in[10];
    const float* bf2 = (const float*)d_in[11];
    float* out = (float*)d_out;

    const int N = N_NODES;
    const int E = in_sizes[1] / 2;
    const int* src = ei;
    const int* dst = ei + E;

    // workspace layout (all 4-byte elements)
    char* p = (char*)d_ws;
    int*   cnt    = (int*)p;                 p += (size_t)50176 * 4;
    float* dis    = (float*)p;               p += (size_t)50176 * 4;
    int*   rowptr = (int*)p;                 p += (size_t)(50176 + 64) * 4;
    int*   cursor = (int*)p;                 p += (size_t)50176 * 4;
    int*   bsum   = (int*)p;                 p += (size_t)256 * 4;
    int*   bbase  = (int*)p;                 p += (size_t)256 * 4;
    int*   col    = (int*)p;                 p += (size_t)E * 4;
    float* A      = (float*)p;               p += (size_t)N * 64 * 4;
    float* B      = (float*)p;

    // ---- CSR build + norms ----
    hipMemsetAsync(cnt, 0, (size_t)N * sizeof(int), stream);
    cnt_kernel<<<(E + 255) / 256, 256, 0, stream>>>(dst, E, cnt);
    bsum_kernel<<<NBLK, SCAN_BLK, 0, stream>>>(cnt, bsum, N);
    bscan_kernel<<<1, SCAN_BLK, 0, stream>>>(bsum, bbase, NBLK);
    scatter_scan_kernel<<<NBLK, SCAN_BLK, 0, stream>>>(cnt, bbase, rowptr, cursor, dis, N);
    fill_kernel<<<(E + 255) / 256, 256, 0, stream>>>(src, dst, E, cursor, col);

    const int mmGrid  = (N + 31) / 32;     // 1563 blocks
    const int aggGrid = (N + 3) / 4;

    // ---- Layer 1 ----
    mm_tiled<128, false, false, true><<<mmGrid, 256, 0, stream>>>(x, W1, nullptr, dis, A, N);
    csr_agg_kernel<<<aggGrid, 256, 0, stream>>>(A, rowptr, col, dis, b1, B, N);

    // ---- Layer 2 ----
    mm_tiled<64, false, false, true><<<mmGrid, 256, 0, stream>>>(B, W2, nullptr, dis, A, N);
    csr_agg_kernel<<<aggGrid, 256, 0, stream>>>(A, rowptr, col, dis, b2, B, N);

    // ---- Layer 3 ----
    mm_tiled<64, false, false, true><<<mmGrid, 256, 0, stream>>>(B, W3, nullptr, dis, A, N);
    csr_agg_kernel<<<aggGrid, 256, 0, stream>>>(A, rowptr, col, dis, b3, B, N);

    // ---- fused FFN head ----
    ffn_kernel<<<mmGrid, 256, 0, stream>>>(B, Wf1, bf1, Wf2, bf2, out, N);
}

// Round 9
// 277.127 us; speedup vs baseline: 1.0838x; 1.0838x over previous
//
#include <hip/hip_runtime.h>

#define N_NODES 50000
#define SCAN_BLK 256
#define NBLK ((N_NODES + SCAN_BLK - 1) / SCAN_BLK)   // 196

// ---- CSR build ----
__global__ void cnt_kernel(const int* __restrict__ dst, int E, int* __restrict__ cnt) {
    int e = blockIdx.x * blockDim.x + threadIdx.x;
    if (e < E) atomicAdd(&cnt[dst[e]], 1);
}

__global__ void bsum_kernel(const int* __restrict__ cnt, int* __restrict__ bsum, int n) {
    __shared__ int sh[SCAN_BLK];
    int i = blockIdx.x * SCAN_BLK + threadIdx.x;
    sh[threadIdx.x] = (i < n) ? cnt[i] : 0;
    __syncthreads();
    for (int off = SCAN_BLK / 2; off > 0; off >>= 1) {
        if (threadIdx.x < off) sh[threadIdx.x] += sh[threadIdx.x + off];
        __syncthreads();
    }
    if (threadIdx.x == 0) bsum[blockIdx.x] = sh[0];
}

__global__ void bscan_kernel(const int* __restrict__ bsum, int* __restrict__ bbase, int nblk) {
    __shared__ int sh[SCAN_BLK];
    int tid = threadIdx.x;
    int v = (tid < nblk) ? bsum[tid] : 0;
    sh[tid] = v;
    __syncthreads();
    for (int off = 1; off < SCAN_BLK; off <<= 1) {
        int t = (tid >= off) ? sh[tid - off] : 0;
        __syncthreads();
        sh[tid] += t;
        __syncthreads();
    }
    if (tid < nblk) bbase[tid] = sh[tid] - v;   // exclusive
}

// per-block exclusive scan + rowptr/cursor emit + dis = rsqrt(cnt+1)
__global__ void scatter_scan_kernel(const int* __restrict__ cnt, const int* __restrict__ bbase,
                                    int* __restrict__ rowptr, int* __restrict__ cursor,
                                    float* __restrict__ dis, int n) {
    __shared__ int sh[SCAN_BLK];
    int tid = threadIdx.x;
    int i = blockIdx.x * SCAN_BLK + tid;
    int v = (i < n) ? cnt[i] : 0;
    sh[tid] = v;
    __syncthreads();
    for (int off = 1; off < SCAN_BLK; off <<= 1) {
        int t = (tid >= off) ? sh[tid - off] : 0;
        __syncthreads();
        sh[tid] += t;
        __syncthreads();
    }
    int excl = bbase[blockIdx.x] + sh[tid] - v;
    if (i < n) {
        rowptr[i] = excl;
        cursor[i] = excl;
        dis[i] = rsqrtf((float)v + 1.0f);
        if (i == n - 1) rowptr[n] = excl + v;
    }
}

__global__ void fill_kernel(const int* __restrict__ src, const int* __restrict__ dst,
                            int E, int* __restrict__ cursor, int* __restrict__ col) {
    int e = blockIdx.x * blockDim.x + threadIdx.x;
    if (e < E) {
        int pos = atomicAdd(&cursor[dst[e]], 1);
        col[pos] = src[e];
    }
}

// wave-level CSR row aggregation: returns self + sum of in-neighbor rows, lane j = feature j
__device__ __forceinline__ float agg_row(const float* __restrict__ A, const int* __restrict__ rowptr,
                                         const int* __restrict__ col, int d, int j) {
    const int beg = rowptr[d], end = rowptr[d + 1];
    const int deg = end - beg;
    float acc = A[(size_t)d * 64 + j];   // self-loop
    for (int base = 0; base < deg; base += 64) {
        int idx = base + j;
        int c = (idx < deg) ? col[beg + idx] : 0;
        int m = min(64, deg - base);
        int e = 0;
        for (; e + 8 <= m; e += 8) {
            int s0 = __shfl(c, e + 0), s1 = __shfl(c, e + 1);
            int s2 = __shfl(c, e + 2), s3 = __shfl(c, e + 3);
            int s4 = __shfl(c, e + 4), s5 = __shfl(c, e + 5);
            int s6 = __shfl(c, e + 6), s7 = __shfl(c, e + 7);
            float v0 = A[(size_t)s0 * 64 + j], v1 = A[(size_t)s1 * 64 + j];
            float v2 = A[(size_t)s2 * 64 + j], v3 = A[(size_t)s3 * 64 + j];
            float v4 = A[(size_t)s4 * 64 + j], v5 = A[(size_t)s5 * 64 + j];
            float v6 = A[(size_t)s6 * 64 + j], v7 = A[(size_t)s7 * 64 + j];
            acc += ((v0 + v1) + (v2 + v3)) + ((v4 + v5) + (v6 + v7));
        }
        for (; e < m; ++e) {
            int s = __shfl(c, e);
            acc += A[(size_t)s * 64 + j];
        }
    }
    return acc;
}

// ---- standalone register-blocked MM (layer 1): Y = dis[row] * (X[n,K] @ W[K,64]) ----
template<int K>
__global__ __launch_bounds__(256) void mm_tiled(const float* __restrict__ X,
        const float* __restrict__ W, const float* __restrict__ dis,
        float* __restrict__ Y, int n) {
    constexpr int KC = 64;
    __shared__ float xs[32][KC + 1];
    const int tid = threadIdx.x;
    const int j4 = tid & 15;
    const int rp = tid >> 4;
    const int row0 = blockIdx.x * 32;
    const int col0 = j4 * 4;
    float acc[2][4] = {};

    for (int kc = 0; kc < K; kc += KC) {
        __syncthreads();
        #pragma unroll
        for (int it = 0; it < 2; ++it) {
            int idx = it * 256 + tid;
            int r = idx >> 4, c4 = idx & 15;
            int row = row0 + r;
            float4 v = make_float4(0.f, 0.f, 0.f, 0.f);
            if (row < n) v = *reinterpret_cast<const float4*>(&X[(size_t)row * K + kc + c4 * 4]);
            xs[r][c4 * 4 + 0] = v.x; xs[r][c4 * 4 + 1] = v.y;
            xs[r][c4 * 4 + 2] = v.z; xs[r][c4 * 4 + 3] = v.w;
        }
        __syncthreads();
        #pragma unroll 16
        for (int k = 0; k < KC; ++k) {
            const float4 w = *reinterpret_cast<const float4*>(&W[(size_t)(kc + k) * 64 + col0]);
            const float x0 = xs[rp * 2 + 0][k];
            const float x1 = xs[rp * 2 + 1][k];
            acc[0][0] = fmaf(x0, w.x, acc[0][0]);
            acc[0][1] = fmaf(x0, w.y, acc[0][1]);
            acc[0][2] = fmaf(x0, w.z, acc[0][2]);
            acc[0][3] = fmaf(x0, w.w, acc[0][3]);
            acc[1][0] = fmaf(x1, w.x, acc[1][0]);
            acc[1][1] = fmaf(x1, w.y, acc[1][1]);
            acc[1][2] = fmaf(x1, w.z, acc[1][2]);
            acc[1][3] = fmaf(x1, w.w, acc[1][3]);
        }
    }
    #pragma unroll
    for (int r = 0; r < 2; ++r) {
        int row = row0 + rp * 2 + r;
        if (row < n) {
            float s = dis[row];
            *reinterpret_cast<float4*>(&Y[(size_t)row * 64 + col0]) =
                make_float4(acc[r][0] * s, acc[r][1] * s, acc[r][2] * s, acc[r][3] * s);
        }
    }
}

// ---- fused agg + MM: B_rows(LDS) = relu(dis*(agg(A)+self)+bagg); Y = dis[row]*(B_rows @ W)
__global__ __launch_bounds__(256) void agg_mm_kernel(const float* __restrict__ A,
        const int* __restrict__ rowptr, const int* __restrict__ col,
        const float* __restrict__ dis, const float* __restrict__ bagg,
        const float* __restrict__ W, float* __restrict__ Y, int n) {
    __shared__ float xs[32][65];
    __shared__ float dl[32];
    const int tid = threadIdx.x;
    const int w = tid >> 6, j = tid & 63;
    const int row0 = blockIdx.x * 32;
    const float bj = bagg[j];

    #pragma unroll
    for (int rr = 0; rr < 8; ++rr) {
        int lr = w * 8 + rr;
        int d = row0 + lr;
        if (d < n) {
            float acc = agg_row(A, rowptr, col, d, j);
            float dd = dis[d];
            xs[lr][j] = fmaxf(dd * acc + bj, 0.0f);
            if (j == 0) dl[lr] = dd;
        } else {
            xs[lr][j] = 0.0f;
            if (j == 0) dl[lr] = 0.0f;
        }
    }
    __syncthreads();

    const int j4 = tid & 15;
    const int rp = tid >> 4;
    const int col0 = j4 * 4;
    float acc[2][4] = {};
    #pragma unroll 16
    for (int k = 0; k < 64; ++k) {
        const float4 wv = *reinterpret_cast<const float4*>(&W[(size_t)k * 64 + col0]);
        const float x0 = xs[rp * 2 + 0][k];
        const float x1 = xs[rp * 2 + 1][k];
        acc[0][0] = fmaf(x0, wv.x, acc[0][0]);
        acc[0][1] = fmaf(x0, wv.y, acc[0][1]);
        acc[0][2] = fmaf(x0, wv.z, acc[0][2]);
        acc[0][3] = fmaf(x0, wv.w, acc[0][3]);
        acc[1][0] = fmaf(x1, wv.x, acc[1][0]);
        acc[1][1] = fmaf(x1, wv.y, acc[1][1]);
        acc[1][2] = fmaf(x1, wv.z, acc[1][2]);
        acc[1][3] = fmaf(x1, wv.w, acc[1][3]);
    }
    #pragma unroll
    for (int r = 0; r < 2; ++r) {
        int row = row0 + rp * 2 + r;
        if (row < n) {
            float s = dl[rp * 2 + r];
            *reinterpret_cast<float4*>(&Y[(size_t)row * 64 + col0]) =
                make_float4(acc[r][0] * s, acc[r][1] * s, acc[r][2] * s, acc[r][3] * s);
        }
    }
}

// ---- fused agg + FFN head: B_rows = relu(dis*(agg(A)+self)+b3);
//      out = relu(B_rows@Wf1+bf1) @ Wf2 + bf2
__global__ __launch_bounds__(256) void agg_ffn_kernel(const float* __restrict__ A,
        const int* __restrict__ rowptr, const int* __restrict__ col,
        const float* __restrict__ dis, const float* __restrict__ bagg,
        const float* __restrict__ Wf1, const float* __restrict__ bf1,
        const float* __restrict__ Wf2, const float* __restrict__ bf2,
        float* __restrict__ out, int n) {
    __shared__ float xs[32][65];
    __shared__ float h1[32][65];
    const int tid = threadIdx.x;
    const int w = tid >> 6, j = tid & 63;
    const int row0 = blockIdx.x * 32;
    const float bj = bagg[j];

    #pragma unroll
    for (int rr = 0; rr < 8; ++rr) {
        int lr = w * 8 + rr;
        int d = row0 + lr;
        if (d < n) {
            float acc = agg_row(A, rowptr, col, d, j);
            xs[lr][j] = fmaxf(dis[d] * acc + bj, 0.0f);
        } else {
            xs[lr][j] = 0.0f;
        }
    }
    __syncthreads();

    // stage 1: h1 = relu(xs @ Wf1 + bf1)
    const int j4 = tid & 15;
    const int rp = tid >> 4;
    const int col0 = j4 * 4;
    float acc[2][4] = {};
    #pragma unroll 16
    for (int k = 0; k < 64; ++k) {
        const float4 wv = *reinterpret_cast<const float4*>(&Wf1[(size_t)k * 64 + col0]);
        const float x0 = xs[rp * 2 + 0][k];
        const float x1 = xs[rp * 2 + 1][k];
        acc[0][0] = fmaf(x0, wv.x, acc[0][0]);
        acc[0][1] = fmaf(x0, wv.y, acc[0][1]);
        acc[0][2] = fmaf(x0, wv.z, acc[0][2]);
        acc[0][3] = fmaf(x0, wv.w, acc[0][3]);
        acc[1][0] = fmaf(x1, wv.x, acc[1][0]);
        acc[1][1] = fmaf(x1, wv.y, acc[1][1]);
        acc[1][2] = fmaf(x1, wv.z, acc[1][2]);
        acc[1][3] = fmaf(x1, wv.w, acc[1][3]);
    }
    #pragma unroll
    for (int c = 0; c < 4; ++c) {
        float b = bf1[col0 + c];
        h1[rp * 2 + 0][col0 + c] = fmaxf(acc[0][c] + b, 0.0f);
        h1[rp * 2 + 1][col0 + c] = fmaxf(acc[1][c] + b, 0.0f);
    }
    __syncthreads();

    // stage 2: out[row, 0..9] = h1[row,:] @ Wf2 + bf2 ; 8 threads/row, 5 of 8 active
    const int lr = tid >> 3;
    const int cg = tid & 7;
    if (cg < 5) {
        float a0 = bf2[cg * 2 + 0], a1 = bf2[cg * 2 + 1];
        #pragma unroll 16
        for (int k = 0; k < 64; ++k) {
            float xv = h1[lr][k];
            a0 = fmaf(xv, Wf2[(size_t)k * 10 + cg * 2 + 0], a0);
            a1 = fmaf(xv, Wf2[(size_t)k * 10 + cg * 2 + 1], a1);
        }
        int row = row0 + lr;
        if (row < n) {
            out[(size_t)row * 10 + cg * 2 + 0] = a0;
            out[(size_t)row * 10 + cg * 2 + 1] = a1;
        }
    }
}

extern "C" void kernel_launch(void* const* d_in, const int* in_sizes, int n_in,
                              void* d_out, int out_size, void* d_ws, size_t ws_size,
                              hipStream_t stream) {
    const float* x   = (const float*)d_in[0];
    const int*   ei  = (const int*)d_in[1];
    const float* W1  = (const float*)d_in[2];
    const float* b1  = (const float*)d_in[3];
    const float* W2  = (const float*)d_in[4];
    const float* b2  = (const float*)d_in[5];
    const float* W3  = (const float*)d_in[6];
    const float* b3  = (const float*)d_in[7];
    const float* Wf1 = (const float*)d_in[8];
    const float* bf1 = (const float*)d_in[9];
    const float* Wf2 = (const float*)d_in[10];
    const float* bf2 = (const float*)d_in[11];
    float* out = (float*)d_out;

    const int N = N_NODES;
    const int E = in_sizes[1] / 2;
    const int* src = ei;
    const int* dst = ei + E;

    // workspace layout (all 4-byte elements)
    char* p = (char*)d_ws;
    int*   cnt    = (int*)p;                 p += (size_t)50176 * 4;
    float* dis    = (float*)p;               p += (size_t)50176 * 4;
    int*   rowptr = (int*)p;                 p += (size_t)(50176 + 64) * 4;
    int*   cursor = (int*)p;                 p += (size_t)50176 * 4;
    int*   bsum   = (int*)p;                 p += (size_t)256 * 4;
    int*   bbase  = (int*)p;                 p += (size_t)256 * 4;
    int*   col    = (int*)p;                 p += (size_t)E * 4;
    float* A1     = (float*)p;               p += (size_t)N * 64 * 4;
    float* A2     = (float*)p;

    // ---- CSR build + norms ----
    hipMemsetAsync(cnt, 0, (size_t)N * sizeof(int), stream);
    cnt_kernel<<<(E + 255) / 256, 256, 0, stream>>>(dst, E, cnt);
    bsum_kernel<<<NBLK, SCAN_BLK, 0, stream>>>(cnt, bsum, N);
    bscan_kernel<<<1, SCAN_BLK, 0, stream>>>(bsum, bbase, NBLK);
    scatter_scan_kernel<<<NBLK, SCAN_BLK, 0, stream>>>(cnt, bbase, rowptr, cursor, dis, N);
    fill_kernel<<<(E + 255) / 256, 256, 0, stream>>>(src, dst, E, cursor, col);

    const int grid32 = (N + 31) / 32;      // 1563 blocks

    // A1 = dis * (x @ W1)
    mm_tiled<128><<<grid32, 256, 0, stream>>>(x, W1, dis, A1, N);
    // A2 = dis * (relu(dis*(agg(A1)+self)+b1) @ W2)
    agg_mm_kernel<<<grid32, 256, 0, stream>>>(A1, rowptr, col, dis, b1, W2, A2, N);
    // A1 = dis * (relu(dis*(agg(A2)+self)+b2) @ W3)
    agg_mm_kernel<<<grid32, 256, 0, stream>>>(A2, rowptr, col, dis, b2, W3, A1, N);
    // out = ffn(relu(dis*(agg(A1)+self)+b3))
    agg_ffn_kernel<<<grid32, 256, 0, stream>>>(A1, rowptr, col, dis, b3,
                                               Wf1, bf1, Wf2, bf2, out, N);
}